// Round 7
// baseline (659.338 us; speedup 1.0000x reference)
//
#include <hip/hip_runtime.h>
#include <hip/hip_bf16.h>

typedef _Float16 f16;
typedef _Float16 f16x8 __attribute__((ext_vector_type(8)));
typedef _Float16 f16x4 __attribute__((ext_vector_type(4)));
typedef float    f32x4 __attribute__((ext_vector_type(4)));

#define HDIM 128
#define IDIM 4
#define TLEN 512

__device__ __forceinline__ float sigm(float x){
  return 1.0f / (1.0f + __expf(-x));
}
__device__ __forceinline__ float tanh_fast(float x){
  return 1.0f - 2.0f / (1.0f + __expf(2.0f*x));
}

// 256 blocks x 1024 threads (16 waves, 4/SIMD). Block = 1 direction x 2 chains.
// Wave pair p=(wid&7): wave r=0 owns tiles {p,p+8} (i,f), r=1 owns {p+16,p+24} (g,o).
// 10 MFMA/wave/step (K=160 ext: [h|x|1] @ [Whh^T;Wih^T;bias]). Raw gates exchanged
// via LDS; activation: wave r handles chain r for units [16p,16p+16). 2 barriers/step.
__global__ __launch_bounds__(1024, 4) void bilstm_v4(
    const float* __restrict__ x,
    const float* __restrict__ Wih_f, const float* __restrict__ Whh_f,
    const float* __restrict__ bih_f, const float* __restrict__ bhh_f,
    const float* __restrict__ Wih_b, const float* __restrict__ Whh_b,
    const float* __restrict__ bih_b, const float* __restrict__ bhh_b,
    float* __restrict__ out)
{
  __shared__ __align__(16) f16 xs16[2][TLEN][IDIM];   // 8 KB x (f16), 2 chains
  __shared__ __align__(16) f16 ha[4][64][8];          // 4 KB h in A-frag layout
  __shared__ __align__(16) float graw[2][8][16][4];   // 4 KB raw gates [ch][p][unit][gate]

  const int tid = threadIdx.x;
  const int wid = tid >> 6;         // wave 0..15
  const int l   = tid & 63;
  const int c16 = l & 15;
  const int p   = wid & 7;          // unit-range pair
  const int r   = wid >> 3;         // 0: i,f tiles; 1: g,o tiles (also chain for act)
  const int dir = blockIdx.x >> 7;
  const int b0  = (blockIdx.x & 127) * 2;

  const float* Wih = dir ? Wih_b : Wih_f;
  const float* Whh = dir ? Whh_b : Whh_f;
  const float* bih = dir ? bih_b : bih_f;
  const float* bhh = dir ? bhh_b : bhh_f;

  const int t0 = p + r*16;          // tile indices owned (gate col = t*16 + c16)
  const int t1 = t0 + 8;

  // ---- one-time: B fragments for 2 tiles x 5 K-frags ----
  f16x8 bfrag[2][5];
  #pragma unroll
  for (int q = 0; q < 2; ++q){
    const int gn = (q ? t1 : t0)*16 + c16;
    #pragma unroll
    for (int ks = 0; ks < 4; ++ks){
      const float* pp = Whh + gn*HDIM + ks*32 + (l>>4)*8;
      float4 qa = ((const float4*)pp)[0];
      float4 qb = ((const float4*)pp)[1];
      f16x8 v = { (f16)qa.x,(f16)qa.y,(f16)qa.z,(f16)qa.w,
                  (f16)qb.x,(f16)qb.y,(f16)qb.z,(f16)qb.w };
      bfrag[q][ks] = v;
    }
    f16x8 v4 = (f16x8)(f16)0.0f;
    if (l < 16){
      const float4 wq = *(const float4*)(Wih + gn*IDIM);
      const float bb = bih[gn] + bhh[gn];
      v4[0] = (f16)wq.x; v4[1] = (f16)wq.y;
      v4[2] = (f16)wq.z; v4[3] = (f16)wq.w;
      v4[4] = (f16)bb;
    }
    bfrag[q][4] = v4;
  }
  #pragma unroll
  for (int q = 0; q < 2; ++q)
    #pragma unroll
    for (int ks = 0; ks < 5; ++ks)
      asm("" : "+v"(bfrag[q][ks]));

  // ---- stage x as f16; zero ha ----
  {
    const int ch = tid >> 9, i = tid & 511;
    const float4 v = ((const float4*)(x + (size_t)(b0+ch)*TLEN*IDIM))[i];
    f16x4 hv = { (f16)v.x, (f16)v.y, (f16)v.z, (f16)v.w };
    *(f16x4*)&xs16[ch][i][0] = hv;
  }
  ((int*)ha)[tid] = 0;              // 4 KB = 1024 ints
  __syncthreads();

  float cst = 0.0f, hout = 0.0f;    // lanes l<16: state of (chain r, unit 16p+c16)

  int tt = dir ? (TLEN-1) : 0;
  const int dt = dir ? -1 : 1;
  const int g0 = 2*r, g1 = 2*r + 1; // gate slots written
  const int kse = p >> 1;                                   // ha write ks
  const int Gw  = r + ((2*(p&1) + (c16>>3)) & 3) * 16;      // ha write lane-row
  const int ew  = c16 & 7;                                  // ha write elem

  for (int s = 0; s < TLEN; ++s){
    // A fragments (broadcast-friendly b128, 2-way max aliasing)
    f16x8 a0 = *(const f16x8*)&ha[0][l][0];
    f16x8 a1 = *(const f16x8*)&ha[1][l][0];
    f16x8 a2 = *(const f16x8*)&ha[2][l][0];
    f16x8 a3 = *(const f16x8*)&ha[3][l][0];
    // x/bias ext fragment: lane 0 = chain0, lane 1 = chain1
    f16x4 xq0 = *(const f16x4*)&xs16[0][tt][0];
    f16x4 xq1 = *(const f16x4*)&xs16[1][tt][0];
    f16x4 zq  = (f16x4)(f16)0.0f;
    f16x4 sel = (l == 0) ? xq0 : ((l == 1) ? xq1 : zq);
    f16x8 a4  = (f16x8)(f16)0.0f;
    a4[0] = sel[0]; a4[1] = sel[1]; a4[2] = sel[2]; a4[3] = sel[3];
    a4[4] = (l < 2) ? (f16)1.0f : (f16)0.0f;

    const f32x4 zero4 = { 0.f, 0.f, 0.f, 0.f };
    __builtin_amdgcn_s_setprio(1);
    f32x4 acc0 = __builtin_amdgcn_mfma_f32_16x16x32_f16(a0, bfrag[0][0], zero4, 0,0,0);
    f32x4 acc1 = __builtin_amdgcn_mfma_f32_16x16x32_f16(a0, bfrag[1][0], zero4, 0,0,0);
    acc0 = __builtin_amdgcn_mfma_f32_16x16x32_f16(a1, bfrag[0][1], acc0, 0,0,0);
    acc1 = __builtin_amdgcn_mfma_f32_16x16x32_f16(a1, bfrag[1][1], acc1, 0,0,0);
    acc0 = __builtin_amdgcn_mfma_f32_16x16x32_f16(a2, bfrag[0][2], acc0, 0,0,0);
    acc1 = __builtin_amdgcn_mfma_f32_16x16x32_f16(a2, bfrag[1][2], acc1, 0,0,0);
    acc0 = __builtin_amdgcn_mfma_f32_16x16x32_f16(a3, bfrag[0][3], acc0, 0,0,0);
    acc1 = __builtin_amdgcn_mfma_f32_16x16x32_f16(a3, bfrag[1][3], acc1, 0,0,0);
    acc0 = __builtin_amdgcn_mfma_f32_16x16x32_f16(a4, bfrag[0][4], acc0, 0,0,0);
    acc1 = __builtin_amdgcn_mfma_f32_16x16x32_f16(a4, bfrag[1][4], acc1, 0,0,0);
    __builtin_amdgcn_s_setprio(0);

    // publish raw gates: rows 0,1 live in lanes 0-15 regs .x,.y
    if (l < 16){
      graw[0][p][c16][g0] = acc0.x;
      graw[1][p][c16][g0] = acc0.y;
      graw[0][p][c16][g1] = acc1.x;
      graw[1][p][c16][g1] = acc1.y;
    }
    __syncthreads();                 // bar1: gates ready

    // activation: wave r handles chain r, units [16p, 16p+16)
    if (l < 16){
      const float4 gv = *(const float4*)&graw[r][p][c16][0];  // {i,f,g,o}
      float iv = sigm(gv.x);
      float fv = sigm(gv.y);
      float gg = tanh_fast(gv.z);
      float ov = sigm(gv.w);
      cst  = fv*cst + iv*gg;
      hout = ov * tanh_fast(cst);
      ha[kse][Gw][ew] = (f16)hout;   // single buffer: bar1 separates from reads
    }
    tt += dt;
    __syncthreads();                 // bar2: h ready for next step
  }

  // final h_T -> out[b0+r][dir*128 + 16p + c16]
  if (l < 16){
    out[(size_t)(b0+r)*(2*HDIM) + dir*HDIM + p*16 + c16] = hout;
  }
}

extern "C" void kernel_launch(void* const* d_in, const int* in_sizes, int n_in,
                              void* d_out, int out_size, void* d_ws, size_t ws_size,
                              hipStream_t stream)
{
  const float* x     = (const float*)d_in[0];
  const float* Wih_f = (const float*)d_in[1];
  const float* Whh_f = (const float*)d_in[2];
  const float* bih_f = (const float*)d_in[3];
  const float* bhh_f = (const float*)d_in[4];
  const float* Wih_b = (const float*)d_in[5];
  const float* Whh_b = (const float*)d_in[6];
  const float* bih_b = (const float*)d_in[7];
  const float* bhh_b = (const float*)d_in[8];

  bilstm_v4<<<dim3(256), dim3(1024), 0, stream>>>(
      x, Wih_f, Whh_f, bih_f, bhh_f, Wih_b, Whh_b, bih_b, bhh_b,
      (float*)d_out);
}

// Round 8
// 454.318 us; speedup vs baseline: 1.4513x; 1.4513x over previous
//
#include <hip/hip_runtime.h>
#include <hip/hip_bf16.h>

typedef _Float16 f16;
typedef _Float16 f16x8 __attribute__((ext_vector_type(8)));
typedef _Float16 f16x4 __attribute__((ext_vector_type(4)));
typedef float    f32x4 __attribute__((ext_vector_type(4)));

#define HDIM 128
#define IDIM 4
#define TLEN 512

#if __has_builtin(__builtin_amdgcn_rcpf)
__device__ __forceinline__ float frcp(float x){ return __builtin_amdgcn_rcpf(x); }
#else
__device__ __forceinline__ float frcp(float x){ return 1.0f / x; }
#endif

__device__ __forceinline__ float sigm(float x){
  // rcp(1 + 2^(-x*log2e)) : mul, exp, add, rcp
  return frcp(1.0f + __builtin_exp2f(x * -1.442695041f));
}
__device__ __forceinline__ float tanh_fast(float x){
  // 1 - 2*rcp(1 + 2^(x*2*log2e)) : mul, exp, add, rcp, fma
  return 1.0f - 2.0f * frcp(1.0f + __builtin_exp2f(x * 2.885390082f));
}

// Round-6 structure + tail cuts. Block = 1 direction x 2 chains; 8 waves;
// wave w owns gate tiles {w,w+8,w+16,w+24} (all 4 gates of units [16w,16w+16)).
// K=160 ext MFMA: gates = [h|x|1] @ [Whh^T;Wih^T;bias]. One barrier/step.
// Both chains' activation on lanes 0-15 (acc.x/.y) - no bpermute.
// a4 (x/bias frag) built one step ahead; MFMA chains start with the LDS-free a4.
__global__ __launch_bounds__(512, 2) void bilstm_v5(
    const float* __restrict__ x,
    const float* __restrict__ Wih_f, const float* __restrict__ Whh_f,
    const float* __restrict__ bih_f, const float* __restrict__ bhh_f,
    const float* __restrict__ Wih_b, const float* __restrict__ Whh_b,
    const float* __restrict__ bih_b, const float* __restrict__ bhh_b,
    float* __restrict__ out)
{
  __shared__ __align__(16) f16 xs16[2][TLEN][IDIM];  // 8 KB x (f16), both chains
  __shared__ __align__(16) f16 ha[2][4][64][8];      // 8 KB h in A-frag layout, dbuf

  const int tid = threadIdx.x;
  const int w   = tid >> 6;        // wave 0..7
  const int l   = tid & 63;
  const int c16 = l & 15;
  const int dir = blockIdx.x >> 7;
  const int b0  = (blockIdx.x & 127) * 2;

  const float* Wih = dir ? Wih_b : Wih_f;
  const float* Whh = dir ? Whh_b : Whh_f;
  const float* bih = dir ? bih_b : bih_f;
  const float* bhh = dir ? bhh_b : bhh_f;

  // ---- one-time: B fragments (4 tiles x 5 K-frags; frag 4 = [Wih^T;bias]) ----
  f16x8 bfrag[4][5];
  #pragma unroll
  for (int t = 0; t < 4; ++t){
    const int gn = t*128 + w*16 + c16;
    #pragma unroll
    for (int ks = 0; ks < 4; ++ks){
      const float* p = Whh + gn*HDIM + ks*32 + (l>>4)*8;
      float4 qa = ((const float4*)p)[0];
      float4 qb = ((const float4*)p)[1];
      f16x8 v = { (f16)qa.x,(f16)qa.y,(f16)qa.z,(f16)qa.w,
                  (f16)qb.x,(f16)qb.y,(f16)qb.z,(f16)qb.w };
      bfrag[t][ks] = v;
    }
    f16x8 v4 = (f16x8)(f16)0.0f;
    if (l < 16){
      const float4 wq = *(const float4*)(Wih + gn*IDIM);
      const float bb = bih[gn] + bhh[gn];
      v4[0] = (f16)wq.x; v4[1] = (f16)wq.y;
      v4[2] = (f16)wq.z; v4[3] = (f16)wq.w;
      v4[4] = (f16)bb;
    }
    bfrag[t][4] = v4;
  }
  #pragma unroll
  for (int t = 0; t < 4; ++t)
    #pragma unroll
    for (int ks = 0; ks < 5; ++ks)
      asm("" : "+v"(bfrag[t][ks]));

  // ---- stage x as f16; zero ha ----
  {
    const float4* src0 = (const float4*)(x + (size_t)(b0+0)*TLEN*IDIM);
    const float4* src1 = (const float4*)(x + (size_t)(b0+1)*TLEN*IDIM);
    float4 v0 = src0[tid], v1 = src1[tid];
    f16x4 h0 = { (f16)v0.x, (f16)v0.y, (f16)v0.z, (f16)v0.w };
    f16x4 h1 = { (f16)v1.x, (f16)v1.y, (f16)v1.z, (f16)v1.w };
    *(f16x4*)&xs16[0][tid][0] = h0;
    *(f16x4*)&xs16[1][tid][0] = h1;
  }
  {
    int* hz = (int*)ha;
    hz[tid] = 0; hz[tid+512] = 0; hz[tid+1024] = 0; hz[tid+1536] = 0;
  }
  __syncthreads();

  float c0 = 0.f, c1 = 0.f, h0o = 0.f, h1o = 0.f;  // lanes l<16
  int tt = dir ? (TLEN-1) : 0;
  const int dt = dir ? -1 : 1;

  const int kse = w >> 1;                                  // ha write ks
  const int Gw0 = ((2*w + (c16 >> 3)) & 3) * 16;           // chain0 row; chain1 = +1
  const int ew  = c16 & 7;

  const f16x4 zq = (f16x4)(f16)0.0f;

#define BUILD_A4(A4, T)                                                       \
  {                                                                           \
    f16x4 xq0 = *(const f16x4*)&xs16[0][(T)][0];                              \
    f16x4 xq1 = *(const f16x4*)&xs16[1][(T)][0];                              \
    f16x4 sel = (l == 0) ? xq0 : ((l == 1) ? xq1 : zq);                       \
    A4 = (f16x8)(f16)0.0f;                                                    \
    A4[0] = sel[0]; A4[1] = sel[1]; A4[2] = sel[2]; A4[3] = sel[3];           \
    A4[4] = (l < 2) ? (f16)1.0f : (f16)0.0f;                                  \
  }

  f16x8 a4;
  BUILD_A4(a4, tt)
  tt += dt;

#define STEP(RB, WB)                                                          \
  {                                                                           \
    f16x8 a0 = *(const f16x8*)&ha[RB][0][l][0];                               \
    f16x8 a1 = *(const f16x8*)&ha[RB][1][l][0];                               \
    f16x8 a2 = *(const f16x8*)&ha[RB][2][l][0];                               \
    f16x8 a3 = *(const f16x8*)&ha[RB][3][l][0];                               \
    const f32x4 zero4 = { 0.f, 0.f, 0.f, 0.f };                               \
    f32x4 acc[4];                                                             \
    __builtin_amdgcn_s_setprio(1);                                            \
    _Pragma("unroll")                                                         \
    for (int t = 0; t < 4; ++t){                                              \
      acc[t] = __builtin_amdgcn_mfma_f32_16x16x32_f16(a4, bfrag[t][4], zero4, 0,0,0); \
      acc[t] = __builtin_amdgcn_mfma_f32_16x16x32_f16(a0, bfrag[t][0], acc[t], 0,0,0); \
      acc[t] = __builtin_amdgcn_mfma_f32_16x16x32_f16(a1, bfrag[t][1], acc[t], 0,0,0); \
      acc[t] = __builtin_amdgcn_mfma_f32_16x16x32_f16(a2, bfrag[t][2], acc[t], 0,0,0); \
      acc[t] = __builtin_amdgcn_mfma_f32_16x16x32_f16(a3, bfrag[t][3], acc[t], 0,0,0); \
    }                                                                         \
    __builtin_amdgcn_s_setprio(0);                                            \
    if (l < 16){                                                              \
      float i0 = sigm(acc[0].x), i1 = sigm(acc[0].y);                         \
      float f0 = sigm(acc[1].x), f1 = sigm(acc[1].y);                         \
      float g0 = tanh_fast(acc[2].x), g1 = tanh_fast(acc[2].y);               \
      float o0 = sigm(acc[3].x), o1 = sigm(acc[3].y);                         \
      c0 = f0*c0 + i0*g0;                                                     \
      c1 = f1*c1 + i1*g1;                                                     \
      h0o = o0 * tanh_fast(c0);                                               \
      h1o = o1 * tanh_fast(c1);                                               \
      ha[WB][kse][Gw0][ew]   = (f16)h0o;                                      \
      ha[WB][kse][Gw0+1][ew] = (f16)h1o;                                      \
    }                                                                         \
    BUILD_A4(a4, tt & (TLEN-1))                                               \
    tt += dt;                                                                 \
    __syncthreads();                                                          \
  }

  for (int s = 0; s < TLEN; s += 2){
    STEP(0, 1)
    STEP(1, 0)
  }
#undef STEP
#undef BUILD_A4

  // final h_T -> out[b, dir*128 + j]
  if (l < 16){
    const int j = w*16 + c16;
    out[(size_t)(b0+0)*(2*HDIM) + dir*HDIM + j] = h0o;
    out[(size_t)(b0+1)*(2*HDIM) + dir*HDIM + j] = h1o;
  }
}

extern "C" void kernel_launch(void* const* d_in, const int* in_sizes, int n_in,
                              void* d_out, int out_size, void* d_ws, size_t ws_size,
                              hipStream_t stream)
{
  const float* x     = (const float*)d_in[0];
  const float* Wih_f = (const float*)d_in[1];
  const float* Whh_f = (const float*)d_in[2];
  const float* bih_f = (const float*)d_in[3];
  const float* bhh_f = (const float*)d_in[4];
  const float* Wih_b = (const float*)d_in[5];
  const float* Whh_b = (const float*)d_in[6];
  const float* bih_b = (const float*)d_in[7];
  const float* bhh_b = (const float*)d_in[8];

  bilstm_v5<<<dim3(256), dim3(512), 0, stream>>>(
      x, Wih_f, Whh_f, bih_f, bhh_f, Wih_b, Whh_b, bih_b, bhh_b,
      (float*)d_out);
}